// Round 1
// baseline (375.387 us; speedup 1.0000x reference)
//
#include <hip/hip_runtime.h>
#include <cstdint>
#include <cstddef>

#define N_INST 200
#define HWPIX (448 * 448)        // 200704 pixels per mask
#define W64 (HWPIX / 64)         // 3136 uint64 words per packed mask
#define SIGMA 2.0f

// ---------------------------------------------------------------------------
// K1: bitpack binary fp32 masks -> uint64 words. One wave packs 64 pixels via
// __ballot (64-bit on gfx950). Coalesced 256 B read per wave, 8 B write.
// ---------------------------------------------------------------------------
__global__ void pack_kernel(const float* __restrict__ seg,
                            uint64_t* __restrict__ packed) {
    size_t tid  = (size_t)blockIdx.x * blockDim.x + threadIdx.x;
    size_t wave = tid >> 6;
    int lane    = (int)(threadIdx.x & 63);
    const size_t total_words = (size_t)N_INST * W64;   // 627200, exact multiple
    if (wave >= total_words) return;
    float v = seg[wave * 64 + lane];
    unsigned long long m = __ballot(v > 0.5f);
    if (lane == 0) packed[wave] = m;
}

// ---------------------------------------------------------------------------
// K2: per-mask popcount -> sum_masks (exact integer in fp32).
// One block (256 threads) per mask; packed data is L2-resident (5 MB total).
// ---------------------------------------------------------------------------
__global__ void sum_kernel(const uint64_t* __restrict__ packed,
                           float* __restrict__ sums) {
    int i = blockIdx.x;
    const uint64_t* a = packed + (size_t)i * W64;
    int cnt = 0;
    for (int w = threadIdx.x; w < W64; w += blockDim.x)
        cnt += __popcll(a[w]);
    // wave reduce (wave64)
    for (int off = 32; off; off >>= 1) cnt += __shfl_down(cnt, off, 64);
    __shared__ int partial[4];
    int wid = threadIdx.x >> 6;
    if ((threadIdx.x & 63) == 0) partial[wid] = cnt;
    __syncthreads();
    if (threadIdx.x == 0)
        sums[i] = (float)(partial[0] + partial[1] + partial[2] + partial[3]);
}

// ---------------------------------------------------------------------------
// K3: decay_iou matrix. One wave per (i,j). i<j: popcount(AND) -> IoU * same
// label. i>=j: write 0 (triu semantics; also zero-inits D, since ws is
// poisoned to 0xAA before every call).
// ---------------------------------------------------------------------------
__global__ void pair_kernel(const uint64_t* __restrict__ packed,
                            const float* __restrict__ sums,
                            const int* __restrict__ labels,
                            float* __restrict__ D) {
    int j = blockIdx.x;
    int i = blockIdx.y;
    if (i >= j) {
        if (threadIdx.x == 0) D[i * N_INST + j] = 0.0f;
        return;
    }
    int lane = threadIdx.x;   // block = 64 threads = 1 wave
    const uint64_t* a = packed + (size_t)i * W64;
    const uint64_t* b = packed + (size_t)j * W64;
    int cnt = 0;
    // W64 = 3136 = 49 * 64 -> every lane does exactly 49 iterations
    for (int w = lane; w < W64; w += 64)
        cnt += __popcll(a[w] & b[w]);
    for (int off = 32; off; off >>= 1) cnt += __shfl_down(cnt, off, 64);
    if (lane == 0) {
        float inter = (float)cnt;
        float uni   = sums[i] + sums[j] - inter;
        float iou   = inter / uni;
        float d     = (labels[i] == labels[j]) ? iou : 0.0f;
        D[i * N_INST + j] = d;
    }
}

// ---------------------------------------------------------------------------
// K4: finalize. comp[j] = max_i D[i][j]; then
// decay[j] = exp(SIGMA * min_i(comp[i]^2 - D[i][j]^2))  (exp is monotone, so
// min(exp(x)) == exp(min(x))). Single block, thread j owns column j.
// ---------------------------------------------------------------------------
__global__ void finalize_kernel(const float* __restrict__ D,
                                const float* __restrict__ scores,
                                float* __restrict__ out) {
    __shared__ float comp[N_INST];
    int j = threadIdx.x;
    if (j < N_INST) {
        float c = 0.0f;   // triu column max includes the zero lower triangle
        for (int i = 0; i < N_INST; ++i)
            c = fmaxf(c, D[i * N_INST + j]);
        comp[j] = c;
    }
    __syncthreads();
    if (j < N_INST) {
        float m = 3.4e38f;
        for (int i = 0; i < N_INST; ++i) {
            float d = D[i * N_INST + j];
            float v = comp[i] * comp[i] - d * d;
            m = fminf(m, v);
        }
        out[j] = scores[j] * expf(SIGMA * m);
    }
}

extern "C" void kernel_launch(void* const* d_in, const int* in_sizes, int n_in,
                              void* d_out, int out_size, void* d_ws, size_t ws_size,
                              hipStream_t stream) {
    const float* seg    = (const float*)d_in[0];   // (200,448,448) fp32 binary
    const float* scores = (const float*)d_in[1];   // (200,) fp32
    const int*   labels = (const int*)d_in[2];     // (200,) int32
    float* out = (float*)d_out;                    // (200,) fp32

    // workspace layout
    uint64_t* packed = (uint64_t*)d_ws;                               // 5,017,600 B
    float*    sums   = (float*)((char*)d_ws + (size_t)N_INST * W64 * 8);   // 800 B
    float*    Dmat   = (float*)((char*)sums + 1024);                  // 160,000 B

    // K1: 627200 words * 64 threads = 40,140,800 threads
    {
        const size_t total_threads = (size_t)N_INST * W64 * 64;
        int block = 256;
        int grid  = (int)((total_threads + block - 1) / block);  // 156800
        pack_kernel<<<grid, block, 0, stream>>>(seg, packed);
    }
    // K2: per-mask sums
    sum_kernel<<<N_INST, 256, 0, stream>>>(packed, sums);
    // K3: pairwise decay-IoU (full N x N grid; i>=j blocks just zero D)
    {
        dim3 grid(N_INST, N_INST);
        pair_kernel<<<grid, 64, 0, stream>>>(packed, sums, labels, Dmat);
    }
    // K4: column max + column min + exp
    finalize_kernel<<<1, 256, 0, stream>>>(Dmat, scores, out);
}

// Round 2
// 262.995 us; speedup vs baseline: 1.4274x; 1.4274x over previous
//
#include <hip/hip_runtime.h>
#include <cstdint>
#include <cstddef>

#define N_INST 200
#define HWPIX (448 * 448)        // 200704 pixels per mask
#define W64 (HWPIX / 64)         // 3136 uint64 words per packed mask
#define W16 (HWPIX / 16)         // 12544 uint16 words per packed mask
#define SIGMA 2.0f

// workspace layout (bytes):
//   [0, 5017600)            packed bitmasks (200 * 3136 u64)
//   [5017600, 5018624)      sums_int (200 ints, padded)
//   [5018624, 5178624)      DT: decay matrix TRANSPOSED, DT[j*200+i] (fp32)
#define OFF_SUMS  (5017600)
#define OFF_DT    (5018624)

// ---------------------------------------------------------------------------
// K0: zero sums_int + DT (ws is poisoned 0xAA before every call).
// ---------------------------------------------------------------------------
__global__ void zero_kernel(uint32_t* __restrict__ base) {
    int idx = blockIdx.x * blockDim.x + threadIdx.x;
    const int nwords = (1024 + N_INST * N_INST * 4) / 4;   // sums pad + DT
    if (idx < nwords) base[idx] = 0u;
}

// ---------------------------------------------------------------------------
// K1: bitpack + fused per-mask popcount sum.
// grid = (49, 200): block (bx, mask) packs 4096 consecutive pixels.
// Each thread: 4x float4 = 16 pixels -> one uint16 (little-endian layout makes
// the uint16 array bit-identical to the uint64 word array).
// ---------------------------------------------------------------------------
__global__ void pack_kernel(const float* __restrict__ seg,
                            uint16_t* __restrict__ packed16,
                            int* __restrict__ sums) {
    const int mask = blockIdx.y;
    const int tid  = threadIdx.x;
    const size_t base = (size_t)mask * HWPIX + (size_t)blockIdx.x * 4096 + (size_t)tid * 16;
    const float4* s4 = (const float4*)(seg + base);
    uint32_t m = 0;
    float4 v0 = s4[0], v1 = s4[1], v2 = s4[2], v3 = s4[3];
    m |= (v0.x > 0.5f) ? 1u << 0  : 0u;  m |= (v0.y > 0.5f) ? 1u << 1  : 0u;
    m |= (v0.z > 0.5f) ? 1u << 2  : 0u;  m |= (v0.w > 0.5f) ? 1u << 3  : 0u;
    m |= (v1.x > 0.5f) ? 1u << 4  : 0u;  m |= (v1.y > 0.5f) ? 1u << 5  : 0u;
    m |= (v1.z > 0.5f) ? 1u << 6  : 0u;  m |= (v1.w > 0.5f) ? 1u << 7  : 0u;
    m |= (v2.x > 0.5f) ? 1u << 8  : 0u;  m |= (v2.y > 0.5f) ? 1u << 9  : 0u;
    m |= (v2.z > 0.5f) ? 1u << 10 : 0u;  m |= (v2.w > 0.5f) ? 1u << 11 : 0u;
    m |= (v3.x > 0.5f) ? 1u << 12 : 0u;  m |= (v3.y > 0.5f) ? 1u << 13 : 0u;
    m |= (v3.z > 0.5f) ? 1u << 14 : 0u;  m |= (v3.w > 0.5f) ? 1u << 15 : 0u;
    packed16[(size_t)mask * W16 + blockIdx.x * 256 + tid] = (uint16_t)m;

    // fused popcount-sum
    int cnt = __popc(m);
    for (int off = 32; off; off >>= 1) cnt += __shfl_down(cnt, off, 64);
    __shared__ int partial[4];
    int wid = tid >> 6;
    if ((tid & 63) == 0) partial[wid] = cnt;
    __syncthreads();
    if (tid == 0)
        atomicAdd(&sums[mask], partial[0] + partial[1] + partial[2] + partial[3]);
}

// ---------------------------------------------------------------------------
// K2: pairwise decay-IoU. One WAVE per 2x4 pair tile (rows {i0,i0+1}, cols
// {j0..j0+3}): 6 loads feed 8 AND+POPC pairs -> traffic 1 GB -> 384 MB.
// Tile enumeration covers only tiles intersecting the strict upper triangle:
// cumulative count before jt is jt^2+jt; it in [0, 2jt+2).
// Writes DT[j*200+i] (transposed) so K3 row ops are coalesced.
// ---------------------------------------------------------------------------
#define NTILES 2550   // sum over jt=0..49 of (2*jt+2)

__global__ void pair_kernel(const uint64_t* __restrict__ packed,
                            const int* __restrict__ sums,
                            const int* __restrict__ labels,
                            float* __restrict__ DT) {
    int wt = blockIdx.x * 4 + (threadIdx.x >> 6);   // wave-tile id
    if (wt >= NTILES) return;
    int lane = threadIdx.x & 63;

    // decode wt -> (jt, it):  jt = floor((-1+sqrt(1+4wt))/2)
    int jt = (int)((sqrtf((float)(4 * wt + 1)) - 1.0f) * 0.5f);
    while ((jt + 1) * (jt + 2) <= wt) ++jt;
    while (jt * (jt + 1) > wt) --jt;
    int it = wt - jt * (jt + 1);
    int i0 = 2 * it;          // i0, i0+1 <= 199
    int j0 = 4 * jt;          // j0..j0+3 <= 199

    const uint64_t* A0 = packed + (size_t)i0 * W64;
    const uint64_t* A1 = A0 + W64;
    const uint64_t* B0 = packed + (size_t)j0 * W64;
    const uint64_t* B1 = B0 + W64;
    const uint64_t* B2 = B1 + W64;
    const uint64_t* B3 = B2 + W64;

    int c00 = 0, c01 = 0, c02 = 0, c03 = 0;
    int c10 = 0, c11 = 0, c12 = 0, c13 = 0;
#pragma unroll 7
    for (int iter = 0; iter < 49; ++iter) {
        int k = iter * 64 + lane;
        uint64_t a0 = A0[k], a1 = A1[k];
        uint64_t b0 = B0[k], b1 = B1[k], b2 = B2[k], b3 = B3[k];
        c00 += __popcll(a0 & b0); c01 += __popcll(a0 & b1);
        c02 += __popcll(a0 & b2); c03 += __popcll(a0 & b3);
        c10 += __popcll(a1 & b0); c11 += __popcll(a1 & b1);
        c12 += __popcll(a1 & b2); c13 += __popcll(a1 & b3);
    }
#pragma unroll
    for (int off = 1; off < 64; off <<= 1) {
        c00 += __shfl_xor(c00, off, 64); c01 += __shfl_xor(c01, off, 64);
        c02 += __shfl_xor(c02, off, 64); c03 += __shfl_xor(c03, off, 64);
        c10 += __shfl_xor(c10, off, 64); c11 += __shfl_xor(c11, off, 64);
        c12 += __shfl_xor(c12, off, 64); c13 += __shfl_xor(c13, off, 64);
    }
    if (lane == 0) {
        int cnts[2][4] = {{c00, c01, c02, c03}, {c10, c11, c12, c13}};
#pragma unroll
        for (int r = 0; r < 2; ++r) {
            int i = i0 + r;
            float si = (float)sums[i];
            int li = labels[i];
#pragma unroll
            for (int c = 0; c < 4; ++c) {
                int j = j0 + c;
                if (i < j) {
                    float inter = (float)cnts[r][c];
                    float uni = si + (float)sums[j] - inter;
                    float iou = inter / uni;
                    DT[(size_t)j * N_INST + i] = (li == labels[j]) ? iou : 0.0f;
                }
            }
        }
    }
}

// ---------------------------------------------------------------------------
// K3a: comp[j] = max_i DT[j][i]  (row of DT = column of decay matrix).
// 200 blocks x 64 threads, coalesced row reads.
// ---------------------------------------------------------------------------
__global__ void comp_kernel(const float* __restrict__ DT,
                            float* __restrict__ comp) {
    int j = blockIdx.x;
    int t = threadIdx.x;
    const float* row = DT + (size_t)j * N_INST;
    float m = 0.0f;
    for (int i = t; i < N_INST; i += 64) m = fmaxf(m, row[i]);
#pragma unroll
    for (int off = 1; off < 64; off <<= 1) m = fmaxf(m, __shfl_xor(m, off, 64));
    if (t == 0) comp[j] = m;
}

// ---------------------------------------------------------------------------
// K3b: out[j] = scores[j] * exp(SIGMA * min_i(comp[i]^2 - DT[j][i]^2)).
// (min of exp == exp of min; exp is monotone.)
// ---------------------------------------------------------------------------
__global__ void finalize_kernel(const float* __restrict__ DT,
                                const float* __restrict__ comp,
                                const float* __restrict__ scores,
                                float* __restrict__ out) {
    int j = blockIdx.x;
    int t = threadIdx.x;
    const float* row = DT + (size_t)j * N_INST;
    float m = 3.4e38f;
    for (int i = t; i < N_INST; i += 64) {
        float ci = comp[i];
        float d  = row[i];
        m = fminf(m, ci * ci - d * d);
    }
#pragma unroll
    for (int off = 1; off < 64; off <<= 1) m = fminf(m, __shfl_xor(m, off, 64));
    if (t == 0) out[j] = scores[j] * expf(SIGMA * m);
}

extern "C" void kernel_launch(void* const* d_in, const int* in_sizes, int n_in,
                              void* d_out, int out_size, void* d_ws, size_t ws_size,
                              hipStream_t stream) {
    const float* seg    = (const float*)d_in[0];   // (200,448,448) fp32 binary
    const float* scores = (const float*)d_in[1];   // (200,) fp32
    const int*   labels = (const int*)d_in[2];     // (200,) int32
    float* out = (float*)d_out;                    // (200,) fp32

    uint64_t* packed   = (uint64_t*)d_ws;
    uint16_t* packed16 = (uint16_t*)d_ws;
    int*      sums     = (int*)((char*)d_ws + OFF_SUMS);
    float*    DT       = (float*)((char*)d_ws + OFF_DT);
    float*    comp     = (float*)((char*)d_ws + OFF_SUMS + 800);  // 200 floats inside pad... no:
    // keep comp in its own safe slot after DT:
    comp = (float*)((char*)d_ws + OFF_DT + (size_t)N_INST * N_INST * 4);

    // K0: zero sums + DT
    {
        const int nwords = (1024 + N_INST * N_INST * 4) / 4;
        zero_kernel<<<(nwords + 255) / 256, 256, 0, stream>>>(
            (uint32_t*)((char*)d_ws + OFF_SUMS));
    }
    // K1: pack + fused sums
    {
        dim3 grid(49, N_INST);
        pack_kernel<<<grid, 256, 0, stream>>>(seg, packed16, sums);
    }
    // K2: pairwise decay-IoU (2550 wave-tiles, 4 waves/block)
    pair_kernel<<<(NTILES + 3) / 4, 256, 0, stream>>>(packed, sums, labels, DT);
    // K3a / K3b
    comp_kernel<<<N_INST, 64, 0, stream>>>(DT, comp);
    finalize_kernel<<<N_INST, 64, 0, stream>>>(DT, comp, scores, out);
}